// Round 3
// baseline (710.953 us; speedup 1.0000x reference)
//
#include <hip/hip_runtime.h>
#include <hip/hip_bf16.h>
#include <math.h>

using bf16 = __hip_bfloat16;
typedef __attribute__((ext_vector_type(4))) float f32x4;
typedef __attribute__((ext_vector_type(8))) short s16x8;

#define BM 256
#define BN 256
#define BK 32
#define SLOT 16384  // bf16 elements per ring slot (A 8192 + B 8192)
#define BREG 8192

__device__ __forceinline__ short f2b(float f) {
  bf16 h = __float2bfloat16(f);
  short s; __builtin_memcpy(&s, &h, 2); return s;
}

__device__ __forceinline__ void async16(const bf16* g, bf16* l) {
  __builtin_amdgcn_global_load_lds(
      (const __attribute__((address_space(1))) void*)g,
      (__attribute__((address_space(3))) void*)l, 16, 0, 0);
}

__device__ __forceinline__ f32x4 vmax4(f32x4 a, f32x4 b) {
  f32x4 r;
#pragma unroll
  for (int j = 0; j < 4; j++) r[j] = fmaxf(a[j], b[j]);
  return r;
}

// NT GEMM, bf16 inputs, 256x256 tile, BK=32, 8 waves, 4-deep LDS ring,
// counted-vmcnt pipeline, source-swizzled LDS, setprio. (round-2 kernel, unchanged)
// MODE 0: projection scatter into (H*B,S,hd); MODE 2: PV; MODE 3: row-major
template<int MODE, bool CF32>
__global__ __launch_bounds__(512, 2) void gemm_nt(const bf16* __restrict__ Ain,
    const bf16* __restrict__ Bin, void* __restrict__ Cout,
    int K, int lda, int ldb, int ldc, float alpha)
{
  __shared__ bf16 lds[4 * SLOT];

  const int tid  = threadIdx.x;
  const int lane = tid & 63;
  const int wave = tid >> 6;
  const int quad = lane >> 4;
  const int l16  = lane & 15;

  const int nwg = gridDim.x * gridDim.y * gridDim.z;
  int bid = (blockIdx.z * gridDim.y + blockIdx.y) * gridDim.x + blockIdx.x;
  bid = (bid & 7) * (nwg >> 3) + (bid >> 3);
  const int bx = bid % gridDim.x;
  int rest = bid / gridDim.x;
  const int by = rest % gridDim.y;
  const int bz = rest / gridDim.y;

  size_t aBase = 0, bBase = 0, cBase = 0;
  if (MODE == 2) {
    aBase = (size_t)(bz & 15) * 1048576 + (size_t)(bz >> 4) * 512;
    bBase = (size_t)bz * 262144;
    cBase = (size_t)((bz & 15) * 4 + (bz >> 4)) * 262144;
  }

  const int tileM = by * BM;
  const int tileN = bx * BN;

  const int sRow = tid >> 2;
  const int sQ   = (tid & 3) ^ ((tid >> 3) & 3);
  const int sCol = sQ * 8;
  const size_t aOff0 = aBase + (size_t)(tileM + sRow) * lda + sCol;
  const size_t aOff1 = aOff0 + (size_t)128 * lda;
  const size_t bOff0 = bBase + (size_t)(tileN + sRow) * ldb + sCol;
  const size_t bOff1 = bOff0 + (size_t)128 * ldb;
  const int t8 = tid * 8;

  const int warpRow = (wave >> 2) * 128;
  const int warpCol = (wave & 3) * 64;
  int offA[8], offB[4];
#pragma unroll
  for (int mi = 0; mi < 8; mi++) {
    const int R = warpRow + mi * 16 + l16;
    offA[mi] = R * 32 + ((quad ^ ((R >> 1) & 3)) * 8);
  }
#pragma unroll
  for (int ni = 0; ni < 4; ni++) {
    const int R = warpCol + ni * 16 + l16;
    offB[ni] = BREG + R * 32 + ((quad ^ ((R >> 1) & 3)) * 8);
  }

  f32x4 acc[8][4] = {};
  const int NT = K / BK;

#pragma unroll
  for (int p = 0; p < 3; ++p) {
    bf16* base = lds + p * SLOT;
    const int ks = p * BK;
    async16(Ain + aOff0 + ks, base + t8);
    async16(Ain + aOff1 + ks, base + 4096 + t8);
    async16(Bin + bOff0 + ks, base + BREG + t8);
    async16(Bin + bOff1 + ks, base + BREG + 4096 + t8);
  }
  asm volatile("s_waitcnt vmcnt(8)" ::: "memory");
  __builtin_amdgcn_s_barrier();

  for (int g = 0; g < NT; ++g) {
    if (g + 3 < NT) {
      bf16* base = lds + ((g + 3) & 3) * SLOT;
      const int ks = (g + 3) * BK;
      async16(Ain + aOff0 + ks, base + t8);
      async16(Ain + aOff1 + ks, base + 4096 + t8);
      async16(Bin + bOff0 + ks, base + BREG + t8);
      async16(Bin + bOff1 + ks, base + BREG + 4096 + t8);
    }

    const bf16* lb = lds + (g & 3) * SLOT;
    s16x8 af[8], bfr[4];
#pragma unroll
    for (int mi = 0; mi < 8; mi++) af[mi] = *(const s16x8*)(lb + offA[mi]);
#pragma unroll
    for (int ni = 0; ni < 4; ni++) bfr[ni] = *(const s16x8*)(lb + offB[ni]);

    __builtin_amdgcn_s_setprio(1);
#pragma unroll
    for (int mi = 0; mi < 8; mi++)
#pragma unroll
      for (int ni = 0; ni < 4; ni++)
        acc[mi][ni] = __builtin_amdgcn_mfma_f32_16x16x32_bf16(af[mi], bfr[ni], acc[mi][ni], 0, 0, 0);
    __builtin_amdgcn_s_setprio(0);

    if (g < NT - 1) {
      const int ahead = (g + 3 < NT ? 2 : (g + 2 < NT ? NT - 2 - g : 0));
      if (ahead == 2)      asm volatile("s_waitcnt vmcnt(8)" ::: "memory");
      else if (ahead == 1) asm volatile("s_waitcnt vmcnt(4)" ::: "memory");
      else                 asm volatile("s_waitcnt vmcnt(0)" ::: "memory");
      __builtin_amdgcn_s_barrier();
    }
  }

#pragma unroll
  for (int mi = 0; mi < 8; mi++) {
#pragma unroll
    for (int ni = 0; ni < 4; ni++) {
      f32x4 v = acc[mi][ni];
      const int col = tileN + warpCol + ni * 16 + l16;
#pragma unroll
      for (int r = 0; r < 4; r++) {
        const int row = tileM + warpRow + mi * 16 + quad * 4 + r;
        const float val = v[r] * alpha;
        size_t dst;
        if (MODE == 0) {
          dst = (((size_t)((col >> 9) * 16 + (row & 15)) * 512 + (size_t)(row >> 4)) * 512)
                + (size_t)(col & 511);
        } else {
          dst = cBase + (size_t)row * ldc + (size_t)col;
        }
        if (CF32) ((float*)Cout)[dst] = val;
        else      ((bf16*)Cout)[dst] = __float2bfloat16(val);
      }
    }
  }
}

// ---- fused scores + softmax: per head, C = softmax(Q K^T / sqrt(hd)) ----
// BM=128 x BN=512 (full row per block), BK=32, 3-slot ring, 5 loads/tile.
// Writes fp32 P and bf16 Pb at identical flat offsets (B,S,H,t).
#define SSLOT 20480  // A 4096 + B 16384 bf16 elems
__global__ __launch_bounds__(512, 2) void scores_softmax(
    const bf16* __restrict__ Q, const bf16* __restrict__ Kh,
    float* __restrict__ P, bf16* __restrict__ Pb, float alpha)
{
  __shared__ bf16 lds[3 * SSLOT];  // 122880 B

  const int tid  = threadIdx.x;
  const int lane = tid & 63;
  const int wave = tid >> 6;
  const int quad = lane >> 4;
  const int l16  = lane & 15;

  // grid (1,4,64): nwg=256, bijective XCD swizzle
  int bid = blockIdx.z * 4 + blockIdx.y;
  bid = (bid & 7) * 32 + (bid >> 3);
  const int by = bid & 3;
  const int bz = bid >> 2;

  const size_t aBase = (size_t)bz * 262144;
  const size_t bBase = (size_t)bz * 262144;
  const size_t cBase = (size_t)(bz & 15) * 1048576 + (size_t)(bz >> 4) * 512;
  const int tileM = by * 128;

  const int sRow = tid >> 2;
  const int sQz  = (tid & 3) ^ ((tid >> 3) & 3);
  const int sCol = sQz * 8;
  const size_t aOff = aBase + (size_t)(tileM + sRow) * 512 + sCol;
  const size_t bOff = bBase + (size_t)sRow * 512 + sCol;
  const int t8 = tid * 8;

  const int warpRow = (wave >> 2) * 64;   // 2 waves along M (rows 0..127)
  const int warpCol = (wave & 3) * 128;   // 4 waves along N (cols 0..511)
  int offA[4], offB[8];
#pragma unroll
  for (int mi = 0; mi < 4; mi++) {
    const int R = warpRow + mi * 16 + l16;
    offA[mi] = R * 32 + ((quad ^ ((R >> 1) & 3)) * 8);
  }
#pragma unroll
  for (int ni = 0; ni < 8; ni++) {
    const int R = warpCol + ni * 16 + l16;
    offB[ni] = 4096 + R * 32 + ((quad ^ ((R >> 1) & 3)) * 8);
  }

  f32x4 acc[4][8] = {};

#pragma unroll
  for (int p = 0; p < 2; ++p) {
    bf16* base = lds + p * SSLOT;
    const int ks = p * BK;
    async16(Q + aOff + ks, base + t8);
#pragma unroll
    for (int c = 0; c < 4; c++)
      async16(Kh + bOff + c * 65536 + ks, base + 4096 + c * 4096 + t8);
  }
  asm volatile("s_waitcnt vmcnt(5)" ::: "memory");
  __builtin_amdgcn_s_barrier();

  for (int g = 0; g < 16; ++g) {
    if (g + 2 < 16) {
      bf16* base = lds + ((g + 2) % 3) * SSLOT;
      const int ks = (g + 2) * BK;
      async16(Q + aOff + ks, base + t8);
#pragma unroll
      for (int c = 0; c < 4; c++)
        async16(Kh + bOff + c * 65536 + ks, base + 4096 + c * 4096 + t8);
    }

    const bf16* lb = lds + (g % 3) * SSLOT;
    s16x8 af[4], bfr[8];
#pragma unroll
    for (int mi = 0; mi < 4; mi++) af[mi] = *(const s16x8*)(lb + offA[mi]);
#pragma unroll
    for (int ni = 0; ni < 8; ni++) bfr[ni] = *(const s16x8*)(lb + offB[ni]);

    __builtin_amdgcn_s_setprio(1);
#pragma unroll
    for (int mi = 0; mi < 4; mi++)
#pragma unroll
      for (int ni = 0; ni < 8; ni++)
        acc[mi][ni] = __builtin_amdgcn_mfma_f32_16x16x32_bf16(af[mi], bfr[ni], acc[mi][ni], 0, 0, 0);
    __builtin_amdgcn_s_setprio(0);

    if (g + 2 < 16) {
      asm volatile("s_waitcnt vmcnt(5)" ::: "memory");
      __builtin_amdgcn_s_barrier();
    } else if (g + 1 < 16) {
      asm volatile("s_waitcnt vmcnt(0)" ::: "memory");
      __builtin_amdgcn_s_barrier();
    }
  }

  // ---- in-block softmax over full 512-wide rows ----
  __syncthreads();                       // drain; LDS reused for reductions
  float* red  = (float*)lds;             // [128][4] per-wave row max
  float* red2 = red + 512;               // [128][4] per-wave row sum
  const int wv = wave & 3;

#pragma unroll
  for (int mi = 0; mi < 4; mi++)
#pragma unroll
    for (int ni = 0; ni < 8; ni++) acc[mi][ni] *= alpha;

  f32x4 gm[4];
#pragma unroll
  for (int mi = 0; mi < 4; mi++) {
    f32x4 mx = acc[mi][0];
#pragma unroll
    for (int ni = 1; ni < 8; ni++) mx = vmax4(mx, acc[mi][ni]);
#pragma unroll
    for (int off = 1; off <= 8; off <<= 1) {
      f32x4 o;
#pragma unroll
      for (int r = 0; r < 4; r++) o[r] = __shfl_xor(mx[r], off, 64);
      mx = vmax4(mx, o);
    }
    if (l16 == 0) {
      const int rw = warpRow + mi * 16 + quad * 4;
#pragma unroll
      for (int r = 0; r < 4; r++) red[(rw + r) * 4 + wv] = mx[r];
    }
  }
  __syncthreads();
#pragma unroll
  for (int mi = 0; mi < 4; mi++) {
    const int rw = warpRow + mi * 16 + quad * 4;
#pragma unroll
    for (int r = 0; r < 4; r++) {
      f32x4 p = *(const f32x4*)&red[(rw + r) * 4];
      gm[mi][r] = fmaxf(fmaxf(p[0], p[1]), fmaxf(p[2], p[3]));
    }
  }
  f32x4 sm[4] = {};
#pragma unroll
  for (int mi = 0; mi < 4; mi++)
#pragma unroll
    for (int ni = 0; ni < 8; ni++) {
      f32x4 v = acc[mi][ni];
#pragma unroll
      for (int r = 0; r < 4; r++) v[r] = __expf(v[r] - gm[mi][r]);
      acc[mi][ni] = v;
      sm[mi] += v;
    }
#pragma unroll
  for (int mi = 0; mi < 4; mi++) {
#pragma unroll
    for (int off = 1; off <= 8; off <<= 1) {
      f32x4 o;
#pragma unroll
      for (int r = 0; r < 4; r++) o[r] = __shfl_xor(sm[mi][r], off, 64);
      sm[mi] += o;
    }
    if (l16 == 0) {
      const int rw = warpRow + mi * 16 + quad * 4;
#pragma unroll
      for (int r = 0; r < 4; r++) red2[(rw + r) * 4 + wv] = sm[mi][r];
    }
  }
  __syncthreads();
#pragma unroll
  for (int mi = 0; mi < 4; mi++) {
    const int rw = warpRow + mi * 16 + quad * 4;
#pragma unroll
    for (int r = 0; r < 4; r++) {
      f32x4 p = *(const f32x4*)&red2[(rw + r) * 4];
      gm[mi][r] = 1.f / (p[0] + p[1] + p[2] + p[3]);   // reuse gm as inv
    }
  }
#pragma unroll
  for (int mi = 0; mi < 4; mi++)
#pragma unroll
    for (int ni = 0; ni < 8; ni++) {
      const int col = warpCol + ni * 16 + l16;
#pragma unroll
      for (int r = 0; r < 4; r++) {
        const int row = tileM + warpRow + mi * 16 + quad * 4 + r;
        const size_t idx = cBase + (size_t)row * 2048 + col;
        const float val = acc[mi][ni][r] * gm[mi][r];
        P[idx]  = val;
        Pb[idx] = __float2bfloat16(val);
      }
    }
}

// batched fp32 -> bf16 conversion; 64 elems/thread/iter, 16 loads in flight
struct Conv6 {
  const float* src[6];
  bf16* dst[6];
  int n[6];
};

__global__ __launch_bounds__(256) void convert6(Conv6 a) {
  const int t = blockIdx.y;
  const float* __restrict__ src = a.src[t];
  bf16* __restrict__ dst = a.dst[t];
  const size_t n = (size_t)a.n[t];
  const size_t stride = (size_t)gridDim.x * 256 * 64;
  for (size_t i = ((size_t)blockIdx.x * 256 + threadIdx.x) * 64; i < n; i += stride) {
    f32x4 x[16];
#pragma unroll
    for (int j = 0; j < 16; j++) x[j] = *(const f32x4*)(src + i + j * 4);
    s16x8 r[8];
#pragma unroll
    for (int j = 0; j < 8; j++) {
#pragma unroll
      for (int k = 0; k < 4; k++) {
        r[j][k]     = f2b(x[2 * j][k]);
        r[j][4 + k] = f2b(x[2 * j + 1][k]);
      }
    }
#pragma unroll
    for (int j = 0; j < 8; j++) *(s16x8*)(dst + i + j * 8) = r[j];
  }
}

// batched 512x512 bf16 transpose: VT[n][e][t] = V[n][t][e]
__global__ __launch_bounds__(256) void transpose512(const bf16* __restrict__ V,
                                                    bf16* __restrict__ VT) {
  __shared__ bf16 tile[32][33];
  const int n = blockIdx.z;
  const bf16* src = V + (size_t)n * 262144;
  bf16* dst = VT + (size_t)n * 262144;
  const int x = blockIdx.x * 32 + threadIdx.x;
#pragma unroll
  for (int i = 0; i < 32; i += 8)
    tile[threadIdx.y + i][threadIdx.x] =
        src[(size_t)(blockIdx.y * 32 + threadIdx.y + i) * 512 + x];
  __syncthreads();
  const int tcol = blockIdx.y * 32 + threadIdx.x;
#pragma unroll
  for (int i = 0; i < 32; i += 8)
    dst[(size_t)(blockIdx.x * 32 + threadIdx.y + i) * 512 + tcol] =
        tile[threadIdx.x][threadIdx.y + i];
}

extern "C" void kernel_launch(void* const* d_in, const int* in_sizes, int n_in,
                              void* d_out, int out_size, void* d_ws, size_t ws_size,
                              hipStream_t stream) {
  const float* query = (const float*)d_in[0];  // fp32 (512,16,2048)
  const float* key   = (const float*)d_in[1];
  const float* value = (const float*)d_in[2];
  const float* Wq = (const float*)d_in[3];     // fp32 (2048,2048)
  const float* Wk = (const float*)d_in[4];
  const float* Wv = (const float*)d_in[5];
  const float* Wo = (const float*)d_in[6];
  float* out = (float*)d_out;             // output (S,B,D) fp32
  float* P   = out + 16777216;            // attn_score (B,S,H,t) fp32

  // 32MB scratch slots. Plan (no producer/consumer overlap at any step):
  //  qb->ws0, kb->ws1, vb->p0, Wq/Wk/Wv->p1 | Qh->o0, Kh->o1, Vh->ws0
  //  scores: o0,o1 -> P(fp32) + Pb->ws1 | transpose: ws0 -> VT@o0
  //  PV: ws1 x o0 -> X@ws0 | Wo->ws1 | final: ws0 x ws1 -> out@(o0,o1)
  bf16* ws0 = (bf16*)d_ws;
  bf16* ws1 = ws0 + 16777216;
  bf16* o0  = (bf16*)d_out;
  bf16* o1  = o0 + 16777216;
  bf16* p0  = (bf16*)P;
  bf16* p1  = p0 + 16777216;

  const dim3 blk(256);
  const dim3 gblk(512);
  const float inv_sqrt_hd = 0.04419417382415922f;  // 1/sqrt(512)

  // 1. batch-convert q,k,v + Wq,Wk,Wv to bf16
  Conv6 c;
  c.src[0] = query; c.dst[0] = ws0;           c.n[0] = 16777216;
  c.src[1] = key;   c.dst[1] = ws1;           c.n[1] = 16777216;
  c.src[2] = value; c.dst[2] = p0;            c.n[2] = 16777216;
  c.src[3] = Wq;    c.dst[3] = p1;            c.n[3] = 4194304;
  c.src[4] = Wk;    c.dst[4] = p1 + 4194304;  c.n[4] = 4194304;
  c.src[5] = Wv;    c.dst[5] = p1 + 8388608;  c.n[5] = 4194304;
  convert6<<<dim3(1024, 6), blk, 0, stream>>>(c);

  // 2. projections: (8192x2048) @ W^T, scatter to (H*B,S,hd) bf16
  gemm_nt<0, false><<<dim3(8, 32, 1), gblk, 0, stream>>>(ws0, p1,           o0,  2048, 2048, 2048, 0, 1.0f);  // Q
  gemm_nt<0, false><<<dim3(8, 32, 1), gblk, 0, stream>>>(ws1, p1 + 4194304, o1,  2048, 2048, 2048, 0, 1.0f);  // K
  gemm_nt<0, false><<<dim3(8, 32, 1), gblk, 0, stream>>>(p0,  p1 + 8388608, ws0, 2048, 2048, 2048, 0, 1.0f);  // V

  // 3. fused scores+softmax: P fp32 (final attn layout) + Pb bf16 -> ws1
  scores_softmax<<<dim3(1, 4, 64), gblk, 0, stream>>>(o0, o1, P, ws1, inv_sqrt_hd);

  // 4. V(ws0) -> VT @ o0 (Q heads dead)
  transpose512<<<dim3(16, 16, 64), dim3(32, 8), 0, stream>>>(ws0, o0);

  // 5. PV: A = Pb (ws1, 2048-stride), B = VT (o0) -> X bf16 (B,H,S,hd) @ ws0
  gemm_nt<2, false><<<dim3(2, 2, 64), gblk, 0, stream>>>(ws1, o0, ws0, 512, 2048, 512, 512, 1.0f);

  // 6. convert Wo -> ws1 (Pb dead)
  Conv6 cw;
  for (int i = 0; i < 6; i++) { cw.src[i] = Wo; cw.dst[i] = ws1; cw.n[i] = 4194304; }
  convert6<<<dim3(256, 1), blk, 0, stream>>>(cw);

  // 7. final: out = X @ Wo^T fp32 @ (o0,o1) region; reads only ws -> no race
  gemm_nt<3, true><<<dim3(8, 32, 1), gblk, 0, stream>>>(ws0, ws1, out, 2048, 2048, 2048, 2048, 1.0f);
}

// Round 5
// 655.096 us; speedup vs baseline: 1.0853x; 1.0853x over previous
//
#include <hip/hip_runtime.h>
#include <hip/hip_bf16.h>
#include <math.h>

using bf16 = __hip_bfloat16;
typedef __attribute__((ext_vector_type(4))) float f32x4;
typedef __attribute__((ext_vector_type(8))) short s16x8;

__device__ __forceinline__ short f2b(float f) {
  bf16 h = __float2bfloat16(f);
  short s; __builtin_memcpy(&s, &h, 2); return s;
}

__device__ __forceinline__ void async16(const bf16* g, bf16* l) {
  __builtin_amdgcn_global_load_lds(
      (const __attribute__((address_space(1))) void*)g,
      (__attribute__((address_space(3))) void*)l, 16, 0, 0);
}

__device__ __forceinline__ f32x4 vmax4(f32x4 a, f32x4 b) {
  f32x4 r;
#pragma unroll
  for (int j = 0; j < 4; j++) r[j] = fmaxf(a[j], b[j]);
  return r;
}

// ============================================================================
// gemm8: NT GEMM, 256x256 tile, BK=64, 8 waves, 2-slot dbuf, 8-phase schedule
// (T3+T4 counted vmcnt + T2 swizzle + T5 setprio). C = alpha * A * B^T.
// Slot layout (bf16 elems): slot S at S*32768; A rows 0..255 at r*64; B at
// +16384. Stage ledger (phases k1..k8 per cycle, cycle computes tiles
// 2it (s0, k1-4) and 2it+1 (s1, k5-8)):
//   k1: s1.Ah1<-2it+1 | k2: s0.Ah0<-2it+2 | k3: s0.Bh0 | k4: s0.Bh1 +vmcnt(6)
//   k5: s0.Ah1<-2it+2 | k6: s1.Ah0<-2it+3 | k7: s1.Bh0 | k8: s1.Bh1 +vmcnt(6)
// Reads: k1: Ah0+Bh0 (12 b128), k2: Bh1 (4), k3: Ah1 (8), k4: none (regs).
// Every stage targets a region whose last ds_read was >=1 barrier earlier;
// every vmcnt(6) completes all loads except the newest 3 pairs, which are
// not read for >=2 more phases. Last cycle: only k1 stage, vmcnt(0) at k4.
// MODE 0: proj scatter to (H*B,S,hd); MODE 2: PV; MODE 3: row-major.
// ============================================================================
#define BAR __builtin_amdgcn_s_barrier()
#define VM6 asm volatile("s_waitcnt vmcnt(6)" ::: "memory")
#define VM0 asm volatile("s_waitcnt vmcnt(0)" ::: "memory")

#define STG_A(S, h, tile) do { \
  const bf16* g_ = aS0 + (size_t)((h) * 128) * lda + (size_t)(tile) * 64; \
  bf16* d_ = lds + (S) * 32768 + (h) * 8192 + stD; \
  async16(g_, d_); async16(g_ + (size_t)64 * lda, d_ + 4096); } while (0)

#define STG_B(S, h, tile) do { \
  const bf16* g_ = bS0 + (size_t)((h) * 128) * ldb + (size_t)(tile) * 64; \
  bf16* d_ = lds + (S) * 32768 + 16384 + (h) * 8192 + stD; \
  async16(g_, d_); async16(g_ + (size_t)64 * ldb, d_ + 4096); } while (0)

#define RD_A(S, qm) do { \
  const bf16* pa0_ = lds + (S) * 32768 + (qm) * 8192 + rdA0; \
  const bf16* pa1_ = lds + (S) * 32768 + (qm) * 8192 + rdA1; \
  _Pragma("unroll") for (int mi = 0; mi < 4; mi++) { \
    af[mi * 2]     = *(const s16x8*)(pa0_ + mi * 1024); \
    af[mi * 2 + 1] = *(const s16x8*)(pa1_ + mi * 1024); } } while (0)

#define RD_B(S, qn, B) do { \
  const bf16* pb0_ = lds + (S) * 32768 + 16384 + (qn) * 8192 + rdB0; \
  const bf16* pb1_ = lds + (S) * 32768 + 16384 + (qn) * 8192 + rdB1; \
  _Pragma("unroll") for (int ni = 0; ni < 2; ni++) { \
    B[ni * 2]     = *(const s16x8*)(pb0_ + ni * 1024); \
    B[ni * 2 + 1] = *(const s16x8*)(pb1_ + ni * 1024); } } while (0)

#define MM(qm, qn, B) do { \
  __builtin_amdgcn_s_setprio(1); \
  _Pragma("unroll") for (int mi = 0; mi < 4; mi++) \
  _Pragma("unroll") for (int ni = 0; ni < 2; ni++) { \
    acc[qm][qn][mi][ni] = __builtin_amdgcn_mfma_f32_16x16x32_bf16(af[mi*2],   B[ni*2],   acc[qm][qn][mi][ni], 0, 0, 0); \
    acc[qm][qn][mi][ni] = __builtin_amdgcn_mfma_f32_16x16x32_bf16(af[mi*2+1], B[ni*2+1], acc[qm][qn][mi][ni], 0, 0, 0); } \
  __builtin_amdgcn_s_setprio(0); } while (0)

#define GROUP(S, OS, st1, stAll, tO, tN) do { \
  RD_A(S, 0); RD_B(S, 0, bf0); \
  if (st1) STG_A(OS, 1, tO); \
  BAR; MM(0, 0, bf0); BAR; \
  RD_B(S, 1, bf1); \
  if (stAll) STG_A(S, 0, tN); \
  BAR; MM(0, 1, bf1); BAR; \
  RD_A(S, 1); \
  if (stAll) STG_B(S, 0, tN); \
  BAR; MM(1, 1, bf1); BAR; \
  if (stAll) { STG_B(S, 1, tN); VM6; } else { VM0; } \
  BAR; MM(1, 0, bf0); BAR; \
} while (0)

template<int MODE, bool CF32>
__global__ __launch_bounds__(512, 2) void gemm8(const bf16* __restrict__ Ain,
    const bf16* __restrict__ Bin, void* __restrict__ Cout,
    int K, int lda, int ldb, int ldc, float alpha)
{
  __shared__ bf16 lds[2 * 32768];  // 128 KiB

  const int tid  = threadIdx.x;
  const int lane = tid & 63;
  const int wave = tid >> 6;
  const int quad = lane >> 4;
  const int l16  = lane & 15;

  // bijective XCD swizzle (nwg = 256)
  const int nwg = gridDim.x * gridDim.y * gridDim.z;
  int bid = (blockIdx.z * gridDim.y + blockIdx.y) * gridDim.x + blockIdx.x;
  bid = (bid & 7) * (nwg >> 3) + (bid >> 3);
  const int bx = bid % gridDim.x;
  int rest = bid / gridDim.x;
  const int by = rest % gridDim.y;
  const int bz = rest / gridDim.y;

  size_t aBase = 0, bBase = 0, cBase = 0;
  if (MODE == 2) {
    aBase = (size_t)(bz & 15) * 1048576 + (size_t)(bz >> 4) * 512;
    bBase = (size_t)bz * 262144;
    cBase = (size_t)((bz & 15) * 4 + (bz >> 4)) * 262144;
  }

  const int tileM = by * 256;
  const int tileN = bx * 256;

  // staging: thread t covers row (t>>3)+l*64 (+h*128), k-group (t&7) with
  // inverse swizzle on the global column so LDS stays linear (rule 21):
  // LDS[R][kg] holds global kg ^ (R&7).
  const int stD = (tid >> 3) * 64 + (tid & 7) * 8;
  const int sgc = ((tid & 7) ^ ((tid >> 3) & 7)) * 8;
  const bf16* aS0 = Ain + aBase + (size_t)(tileM + (tid >> 3)) * lda + sgc;
  const bf16* bS0 = Bin + bBase + (size_t)(tileN + (tid >> 3)) * ldb + sgc;

  // fragment read offsets: frag(mi,ks) at (qm*128+wrow+mi*16+l16)*64 +
  // ((ks*4+quad)^(l16&7))*8 ; ks-flip is XOR 32 (disjoint bit fields)
  const int wrow = (wave >> 2) * 64;
  const int wcol = (wave & 3) * 32;
  const int kg08 = (quad ^ (l16 & 7)) * 8;
  const int rdA0 = (wrow + l16) * 64 + kg08;
  const int rdA1 = rdA0 ^ 32;
  const int rdB0 = (wcol + l16) * 64 + kg08;
  const int rdB1 = rdB0 ^ 32;

  f32x4 acc[2][2][4][2] = {};
  s16x8 af[8], bf0[4], bf1[4];

  const int NI = K / 128;  // cycles; 2 K-tiles (BK=64) per cycle

  // prologue: tile0 all halves + tile1 first 3 halves (oldest-first order)
  STG_A(0, 0, 0); STG_B(0, 0, 0); STG_B(0, 1, 0); STG_A(0, 1, 0);
  STG_A(1, 0, 1); STG_B(1, 0, 1); STG_B(1, 1, 1);
  VM6;  // tile0's 4 halves (oldest 8 loads) complete
  BAR;

  for (int it = 0; it < NI; ++it) {
    const bool sa = (it + 1 < NI);
    GROUP(0, 1, true, sa, 2 * it + 1, 2 * it + 2);
    GROUP(1, 0, sa,   sa, 2 * it + 2, 2 * it + 3);
  }

  // epilogue: C/D layout col=lane&15, row=(lane>>4)*4+reg
#pragma unroll
  for (int qm = 0; qm < 2; qm++)
#pragma unroll
  for (int qn = 0; qn < 2; qn++)
#pragma unroll
  for (int mi = 0; mi < 4; mi++)
#pragma unroll
  for (int ni = 0; ni < 2; ni++) {
    f32x4 v = acc[qm][qn][mi][ni];
    const int col = tileN + qn * 128 + wcol + ni * 16 + l16;
    const int rowb = tileM + qm * 128 + wrow + mi * 16 + quad * 4;
#pragma unroll
    for (int r = 0; r < 4; r++) {
      const int row = rowb + r;
      const float val = v[r] * alpha;
      size_t dst;
      if (MODE == 0) {
        // dest[(h*16+b)][s][e]: h=col>>9, b=row&15, s=row>>4, e=col&511
        dst = (((size_t)((col >> 9) * 16 + (row & 15)) * 512 + (size_t)(row >> 4)) * 512)
              + (size_t)(col & 511);
      } else {
        dst = cBase + (size_t)row * ldc + (size_t)col;
      }
      if (CF32) ((float*)Cout)[dst] = val;
      else      ((bf16*)Cout)[dst] = __float2bfloat16(val);
    }
  }
}

#undef GROUP
#undef MM
#undef RD_A
#undef RD_B
#undef STG_A
#undef STG_B

// ---- fused scores + softmax (round-3 kernel, verified): per head,
// P = softmax(Q K^T * alpha), fp32 + bf16 outputs ----
#define BK 32
#define SSLOT 20480
__global__ __launch_bounds__(512, 2) void scores_softmax(
    const bf16* __restrict__ Q, const bf16* __restrict__ Kh,
    float* __restrict__ P, bf16* __restrict__ Pb, float alpha)
{
  __shared__ bf16 lds[3 * SSLOT];

  const int tid  = threadIdx.x;
  const int lane = tid & 63;
  const int wave = tid >> 6;
  const int quad = lane >> 4;
  const int l16  = lane & 15;

  int bid = blockIdx.z * 4 + blockIdx.y;
  bid = (bid & 7) * 32 + (bid >> 3);
  const int by = bid & 3;
  const int bz = bid >> 2;

  const size_t aBase = (size_t)bz * 262144;
  const size_t bBase = (size_t)bz * 262144;
  const size_t cBase = (size_t)(bz & 15) * 1048576 + (size_t)(bz >> 4) * 512;
  const int tileM = by * 128;

  const int sRow = tid >> 2;
  const int sQz  = (tid & 3) ^ ((tid >> 3) & 3);
  const int sCol = sQz * 8;
  const size_t aOff = aBase + (size_t)(tileM + sRow) * 512 + sCol;
  const size_t bOff = bBase + (size_t)sRow * 512 + sCol;
  const int t8 = tid * 8;

  const int warpRow = (wave >> 2) * 64;
  const int warpCol = (wave & 3) * 128;
  int offA[4], offB[8];
#pragma unroll
  for (int mi = 0; mi < 4; mi++) {
    const int R = warpRow + mi * 16 + l16;
    offA[mi] = R * 32 + ((quad ^ ((R >> 1) & 3)) * 8);
  }
#pragma unroll
  for (int ni = 0; ni < 8; ni++) {
    const int R = warpCol + ni * 16 + l16;
    offB[ni] = 4096 + R * 32 + ((quad ^ ((R >> 1) & 3)) * 8);
  }

  f32x4 acc[4][8] = {};

#pragma unroll
  for (int p = 0; p < 2; ++p) {
    bf16* base = lds + p * SSLOT;
    const int ks = p * BK;
    async16(Q + aOff + ks, base + t8);
#pragma unroll
    for (int c = 0; c < 4; c++)
      async16(Kh + bOff + c * 65536 + ks, base + 4096 + c * 4096 + t8);
  }
  asm volatile("s_waitcnt vmcnt(5)" ::: "memory");
  __builtin_amdgcn_s_barrier();

  for (int g = 0; g < 16; ++g) {
    if (g + 2 < 16) {
      bf16* base = lds + ((g + 2) % 3) * SSLOT;
      const int ks = (g + 2) * BK;
      async16(Q + aOff + ks, base + t8);
#pragma unroll
      for (int c = 0; c < 4; c++)
        async16(Kh + bOff + c * 65536 + ks, base + 4096 + c * 4096 + t8);
    }

    const bf16* lb = lds + (g % 3) * SSLOT;
    s16x8 af[4], bfr[8];
#pragma unroll
    for (int mi = 0; mi < 4; mi++) af[mi] = *(const s16x8*)(lb + offA[mi]);
#pragma unroll
    for (int ni = 0; ni < 8; ni++) bfr[ni] = *(const s16x8*)(lb + offB[ni]);

    __builtin_amdgcn_s_setprio(1);
#pragma unroll
    for (int mi = 0; mi < 4; mi++)
#pragma unroll
      for (int ni = 0; ni < 8; ni++)
        acc[mi][ni] = __builtin_amdgcn_mfma_f32_16x16x32_bf16(af[mi], bfr[ni], acc[mi][ni], 0, 0, 0);
    __builtin_amdgcn_s_setprio(0);

    if (g + 2 < 16) {
      asm volatile("s_waitcnt vmcnt(5)" ::: "memory");
      __builtin_amdgcn_s_barrier();
    } else if (g + 1 < 16) {
      asm volatile("s_waitcnt vmcnt(0)" ::: "memory");
      __builtin_amdgcn_s_barrier();
    }
  }

  __syncthreads();
  float* red  = (float*)lds;
  float* red2 = red + 512;
  const int wv = wave & 3;

#pragma unroll
  for (int mi = 0; mi < 4; mi++)
#pragma unroll
    for (int ni = 0; ni < 8; ni++) acc[mi][ni] *= alpha;

  f32x4 gm[4];
#pragma unroll
  for (int mi = 0; mi < 4; mi++) {
    f32x4 mx = acc[mi][0];
#pragma unroll
    for (int ni = 1; ni < 8; ni++) mx = vmax4(mx, acc[mi][ni]);
#pragma unroll
    for (int off = 1; off <= 8; off <<= 1) {
      f32x4 o;
#pragma unroll
      for (int r = 0; r < 4; r++) o[r] = __shfl_xor(mx[r], off, 64);
      mx = vmax4(mx, o);
    }
    if (l16 == 0) {
      const int rw = warpRow + mi * 16 + quad * 4;
#pragma unroll
      for (int r = 0; r < 4; r++) red[(rw + r) * 4 + wv] = mx[r];
    }
  }
  __syncthreads();
#pragma unroll
  for (int mi = 0; mi < 4; mi++) {
    const int rw = warpRow + mi * 16 + quad * 4;
#pragma unroll
    for (int r = 0; r < 4; r++) {
      f32x4 p = *(const f32x4*)&red[(rw + r) * 4];
      gm[mi][r] = fmaxf(fmaxf(p[0], p[1]), fmaxf(p[2], p[3]));
    }
  }
  f32x4 sm[4] = {};
#pragma unroll
  for (int mi = 0; mi < 4; mi++)
#pragma unroll
    for (int ni = 0; ni < 8; ni++) {
      f32x4 v = acc[mi][ni];
#pragma unroll
      for (int r = 0; r < 4; r++) v[r] = __expf(v[r] - gm[mi][r]);
      acc[mi][ni] = v;
      sm[mi] += v;
    }
#pragma unroll
  for (int mi = 0; mi < 4; mi++) {
#pragma unroll
    for (int off = 1; off <= 8; off <<= 1) {
      f32x4 o;
#pragma unroll
      for (int r = 0; r < 4; r++) o[r] = __shfl_xor(sm[mi][r], off, 64);
      sm[mi] += o;
    }
    if (l16 == 0) {
      const int rw = warpRow + mi * 16 + quad * 4;
#pragma unroll
      for (int r = 0; r < 4; r++) red2[(rw + r) * 4 + wv] = sm[mi][r];
    }
  }
  __syncthreads();
#pragma unroll
  for (int mi = 0; mi < 4; mi++) {
    const int rw = warpRow + mi * 16 + quad * 4;
#pragma unroll
    for (int r = 0; r < 4; r++) {
      f32x4 p = *(const f32x4*)&red2[(rw + r) * 4];
      gm[mi][r] = 1.f / (p[0] + p[1] + p[2] + p[3]);
    }
  }
#pragma unroll
  for (int mi = 0; mi < 4; mi++)
#pragma unroll
    for (int ni = 0; ni < 8; ni++) {
      const int col = warpCol + ni * 16 + l16;
#pragma unroll
      for (int r = 0; r < 4; r++) {
        const int row = tileM + warpRow + mi * 16 + quad * 4 + r;
        const size_t idx = cBase + (size_t)row * 2048 + col;
        const float val = acc[mi][ni][r] * gm[mi][r];
        P[idx]  = val;
        Pb[idx] = __float2bfloat16(val);
      }
    }
}

// ---- fp32 -> bf16 convert, wave-coalesced (lane stride 32B per load instr),
// 16 loads issued before converts; 16384 elems per block-iter ----
struct Conv6 {
  const float* src[6];
  bf16* dst[6];
  int n[6];
};

__global__ __launch_bounds__(256, 4) void convert6(Conv6 a) {
  const int t = blockIdx.y;
  const float* __restrict__ src = a.src[t];
  bf16* __restrict__ dst = a.dst[t];
  const size_t n = (size_t)a.n[t];
  for (size_t base = (size_t)blockIdx.x * 16384; base < n;
       base += (size_t)gridDim.x * 16384) {
    const size_t o = base + (size_t)threadIdx.x * 8;
    f32x4 x[8], y[8];
#pragma unroll
    for (int j = 0; j < 8; j++) {
      x[j] = *(const f32x4*)(src + o + j * 2048);
      y[j] = *(const f32x4*)(src + o + j * 2048 + 4);
    }
#pragma unroll
    for (int j = 0; j < 8; j++) {
      s16x8 r;
#pragma unroll
      for (int k = 0; k < 4; k++) {
        r[k]     = f2b(x[j][k]);
        r[4 + k] = f2b(y[j][k]);
      }
      *(s16x8*)(dst + o + j * 2048) = r;
    }
  }
}

// batched 512x512 bf16 transpose: VT[n][e][t] = V[n][t][e]
__global__ __launch_bounds__(256) void transpose512(const bf16* __restrict__ V,
                                                    bf16* __restrict__ VT) {
  __shared__ bf16 tile[32][33];
  const int n = blockIdx.z;
  const bf16* src = V + (size_t)n * 262144;
  bf16* dst = VT + (size_t)n * 262144;
  const int x = blockIdx.x * 32 + threadIdx.x;
#pragma unroll
  for (int i = 0; i < 32; i += 8)
    tile[threadIdx.y + i][threadIdx.x] =
        src[(size_t)(blockIdx.y * 32 + threadIdx.y + i) * 512 + x];
  __syncthreads();
  const int tcol = blockIdx.y * 32 + threadIdx.x;
#pragma unroll
  for (int i = 0; i < 32; i += 8)
    dst[(size_t)(blockIdx.x * 32 + threadIdx.y + i) * 512 + tcol] =
        tile[threadIdx.x][threadIdx.y + i];
}

extern "C" void kernel_launch(void* const* d_in, const int* in_sizes, int n_in,
                              void* d_out, int out_size, void* d_ws, size_t ws_size,
                              hipStream_t stream) {
  const float* query = (const float*)d_in[0];  // fp32 (512,16,2048)
  const float* key   = (const float*)d_in[1];
  const float* value = (const float*)d_in[2];
  const float* Wq = (const float*)d_in[3];     // fp32 (2048,2048)
  const float* Wk = (const float*)d_in[4];
  const float* Wv = (const float*)d_in[5];
  const float* Wo = (const float*)d_in[6];
  float* out = (float*)d_out;
  float* P   = out + 16777216;

  // 32MB scratch slots. Plan (no producer/consumer overlap at any step):
  //  qb->ws0, kb->ws1, vb->p0, Wq/Wk/Wv->p1 | Qh->o0, Kh->o1, Vh->ws0
  //  scores: o0,o1 -> P(fp32) + Pb->ws1 | transpose: ws0 -> VT@o0
  //  PV: ws1 x o0 -> X@ws0 | Wo->ws1 | final: ws0 x ws1 -> out@(o0,o1)
  bf16* ws0 = (bf16*)d_ws;
  bf16* ws1 = ws0 + 16777216;
  bf16* o0  = (bf16*)d_out;
  bf16* o1  = o0 + 16777216;
  bf16* p0  = (bf16*)P;
  bf16* p1  = p0 + 16777216;

  const dim3 blk(256);
  const dim3 gblk(512);
  const float inv_sqrt_hd = 0.04419417382415922f;  // 1/sqrt(512)

  // 1. batch-convert q,k,v + Wq,Wk,Wv to bf16
  Conv6 c;
  c.src[0] = query; c.dst[0] = ws0;           c.n[0] = 16777216;
  c.src[1] = key;   c.dst[1] = ws1;           c.n[1] = 16777216;
  c.src[2] = value; c.dst[2] = p0;            c.n[2] = 16777216;
  c.src[3] = Wq;    c.dst[3] = p1;            c.n[3] = 4194304;
  c.src[4] = Wk;    c.dst[4] = p1 + 4194304;  c.n[4] = 4194304;
  c.src[5] = Wv;    c.dst[5] = p1 + 8388608;  c.n[5] = 4194304;
  convert6<<<dim3(1024, 6), blk, 0, stream>>>(c);

  // 2. projections: (8192x2048) @ W^T, scatter to (H*B,S,hd) bf16
  gemm8<0, false><<<dim3(8, 32, 1), gblk, 0, stream>>>(ws0, p1,           o0,  2048, 2048, 2048, 0, 1.0f);
  gemm8<0, false><<<dim3(8, 32, 1), gblk, 0, stream>>>(ws1, p1 + 4194304, o1,  2048, 2048, 2048, 0, 1.0f);
  gemm8<0, false><<<dim3(8, 32, 1), gblk, 0, stream>>>(p0,  p1 + 8388608, ws0, 2048, 2048, 2048, 0, 1.0f);

  // 3. fused scores+softmax: P fp32 (final attn layout) + Pb bf16 -> ws1
  scores_softmax<<<dim3(1, 4, 64), gblk, 0, stream>>>(o0, o1, P, ws1, inv_sqrt_hd);

  // 4. V(ws0) -> VT @ o0 (Q heads dead)
  transpose512<<<dim3(16, 16, 64), dim3(32, 8), 0, stream>>>(ws0, o0);

  // 5. PV: A = Pb (ws1, 2048-stride), B = VT (o0) -> X bf16 (B,H,S,hd) @ ws0
  gemm8<2, false><<<dim3(2, 2, 64), gblk, 0, stream>>>(ws1, o0, ws0, 512, 2048, 512, 512, 1.0f);

  // 6. convert Wo -> ws1 (Pb dead)
  Conv6 cw;
  for (int i = 0; i < 6; i++) { cw.src[i] = Wo; cw.dst[i] = ws1; cw.n[i] = 4194304; }
  convert6<<<dim3(256, 1), blk, 0, stream>>>(cw);

  // 7. final: out = X @ Wo^T fp32 @ (o0,o1) region; reads only ws -> no race
  gemm8<3, true><<<dim3(8, 32, 1), gblk, 0, stream>>>(ws0, ws1, out, 2048, 2048, 2048, 2048, 1.0f);
}

// Round 6
// 625.868 us; speedup vs baseline: 1.1359x; 1.0467x over previous
//
#include <hip/hip_runtime.h>
#include <hip/hip_bf16.h>
#include <math.h>

using bf16 = __hip_bfloat16;
typedef __attribute__((ext_vector_type(4))) float f32x4;
typedef __attribute__((ext_vector_type(8))) short s16x8;
typedef __attribute__((ext_vector_type(4))) short s16x4;

__device__ __forceinline__ short f2b(float f) {
  bf16 h = __float2bfloat16(f);
  short s; __builtin_memcpy(&s, &h, 2); return s;
}

__device__ __forceinline__ void async16(const bf16* g, bf16* l) {
  __builtin_amdgcn_global_load_lds(
      (const __attribute__((address_space(1))) void*)g,
      (__attribute__((address_space(3))) void*)l, 16, 0, 0);
}

__device__ __forceinline__ f32x4 vmax4(f32x4 a, f32x4 b) {
  f32x4 r;
#pragma unroll
  for (int j = 0; j < 4; j++) r[j] = fmaxf(a[j], b[j]);
  return r;
}

// ============================================================================
// gemm8: NT GEMM, 256x256 tile, BK=64, 8 waves, 2-slot dbuf, 8-phase schedule
// (T3+T4 counted vmcnt + T2 swizzle + T5 setprio). C = alpha * A * B^T.
// (round-5 kernel, verified at 655 us total; unchanged this round)
// ============================================================================
#define BAR __builtin_amdgcn_s_barrier()
#define VM6 asm volatile("s_waitcnt vmcnt(6)" ::: "memory")
#define VM0 asm volatile("s_waitcnt vmcnt(0)" ::: "memory")

#define STG_A(S, h, tile) do { \
  const bf16* g_ = aS0 + (size_t)((h) * 128) * lda + (size_t)(tile) * 64; \
  bf16* d_ = lds + (S) * 32768 + (h) * 8192 + stD; \
  async16(g_, d_); async16(g_ + (size_t)64 * lda, d_ + 4096); } while (0)

#define STG_B(S, h, tile) do { \
  const bf16* g_ = bS0 + (size_t)((h) * 128) * ldb + (size_t)(tile) * 64; \
  bf16* d_ = lds + (S) * 32768 + 16384 + (h) * 8192 + stD; \
  async16(g_, d_); async16(g_ + (size_t)64 * ldb, d_ + 4096); } while (0)

#define RD_A(S, qm) do { \
  const bf16* pa0_ = lds + (S) * 32768 + (qm) * 8192 + rdA0; \
  const bf16* pa1_ = lds + (S) * 32768 + (qm) * 8192 + rdA1; \
  _Pragma("unroll") for (int mi = 0; mi < 4; mi++) { \
    af[mi * 2]     = *(const s16x8*)(pa0_ + mi * 1024); \
    af[mi * 2 + 1] = *(const s16x8*)(pa1_ + mi * 1024); } } while (0)

#define RD_B(S, qn, B) do { \
  const bf16* pb0_ = lds + (S) * 32768 + 16384 + (qn) * 8192 + rdB0; \
  const bf16* pb1_ = lds + (S) * 32768 + 16384 + (qn) * 8192 + rdB1; \
  _Pragma("unroll") for (int ni = 0; ni < 2; ni++) { \
    B[ni * 2]     = *(const s16x8*)(pb0_ + ni * 1024); \
    B[ni * 2 + 1] = *(const s16x8*)(pb1_ + ni * 1024); } } while (0)

#define MM(qm, qn, B) do { \
  __builtin_amdgcn_s_setprio(1); \
  _Pragma("unroll") for (int mi = 0; mi < 4; mi++) \
  _Pragma("unroll") for (int ni = 0; ni < 2; ni++) { \
    acc[qm][qn][mi][ni] = __builtin_amdgcn_mfma_f32_16x16x32_bf16(af[mi*2],   B[ni*2],   acc[qm][qn][mi][ni], 0, 0, 0); \
    acc[qm][qn][mi][ni] = __builtin_amdgcn_mfma_f32_16x16x32_bf16(af[mi*2+1], B[ni*2+1], acc[qm][qn][mi][ni], 0, 0, 0); } \
  __builtin_amdgcn_s_setprio(0); } while (0)

#define GROUP(S, OS, st1, stAll, tO, tN) do { \
  RD_A(S, 0); RD_B(S, 0, bf0); \
  if (st1) STG_A(OS, 1, tO); \
  BAR; MM(0, 0, bf0); BAR; \
  RD_B(S, 1, bf1); \
  if (stAll) STG_A(S, 0, tN); \
  BAR; MM(0, 1, bf1); BAR; \
  RD_A(S, 1); \
  if (stAll) STG_B(S, 0, tN); \
  BAR; MM(1, 1, bf1); BAR; \
  if (stAll) { STG_B(S, 1, tN); VM6; } else { VM0; } \
  BAR; MM(1, 0, bf0); BAR; \
} while (0)

template<int MODE, bool CF32>
__global__ __launch_bounds__(512, 2) void gemm8(const bf16* __restrict__ Ain,
    const bf16* __restrict__ Bin, void* __restrict__ Cout,
    int K, int lda, int ldb, int ldc, float alpha)
{
  __shared__ bf16 lds[2 * 32768];  // 128 KiB

  const int tid  = threadIdx.x;
  const int lane = tid & 63;
  const int wave = tid >> 6;
  const int quad = lane >> 4;
  const int l16  = lane & 15;

  // bijective XCD swizzle (nwg = 256)
  const int nwg = gridDim.x * gridDim.y * gridDim.z;
  int bid = (blockIdx.z * gridDim.y + blockIdx.y) * gridDim.x + blockIdx.x;
  bid = (bid & 7) * (nwg >> 3) + (bid >> 3);
  const int bx = bid % gridDim.x;
  int rest = bid / gridDim.x;
  const int by = rest % gridDim.y;
  const int bz = rest / gridDim.y;

  size_t aBase = 0, bBase = 0, cBase = 0;
  if (MODE == 2) {
    aBase = (size_t)(bz & 15) * 1048576 + (size_t)(bz >> 4) * 512;
    bBase = (size_t)bz * 262144;
    cBase = (size_t)((bz & 15) * 4 + (bz >> 4)) * 262144;
  }

  const int tileM = by * 256;
  const int tileN = bx * 256;

  // staging: thread t covers row (t>>3)+l*64 (+h*128), k-group (t&7) with
  // inverse swizzle on the global column so LDS stays linear (rule 21):
  // LDS[R][kg] holds global kg ^ (R&7).
  const int stD = (tid >> 3) * 64 + (tid & 7) * 8;
  const int sgc = ((tid & 7) ^ ((tid >> 3) & 7)) * 8;
  const bf16* aS0 = Ain + aBase + (size_t)(tileM + (tid >> 3)) * lda + sgc;
  const bf16* bS0 = Bin + bBase + (size_t)(tileN + (tid >> 3)) * ldb + sgc;

  // fragment read offsets: frag(mi,ks) at (qm*128+wrow+mi*16+l16)*64 +
  // ((ks*4+quad)^(l16&7))*8 ; ks-flip is XOR 32 (disjoint bit fields)
  const int wrow = (wave >> 2) * 64;
  const int wcol = (wave & 3) * 32;
  const int kg08 = (quad ^ (l16 & 7)) * 8;
  const int rdA0 = (wrow + l16) * 64 + kg08;
  const int rdA1 = rdA0 ^ 32;
  const int rdB0 = (wcol + l16) * 64 + kg08;
  const int rdB1 = rdB0 ^ 32;

  f32x4 acc[2][2][4][2] = {};
  s16x8 af[8], bf0[4], bf1[4];

  const int NI = K / 128;  // cycles; 2 K-tiles (BK=64) per cycle

  // prologue: tile0 all halves + tile1 first 3 halves (oldest-first order)
  STG_A(0, 0, 0); STG_B(0, 0, 0); STG_B(0, 1, 0); STG_A(0, 1, 0);
  STG_A(1, 0, 1); STG_B(1, 0, 1); STG_B(1, 1, 1);
  VM6;  // tile0's 4 halves (oldest 8 loads) complete
  BAR;

  for (int it = 0; it < NI; ++it) {
    const bool sa = (it + 1 < NI);
    GROUP(0, 1, true, sa, 2 * it + 1, 2 * it + 2);
    GROUP(1, 0, sa,   sa, 2 * it + 2, 2 * it + 3);
  }

  // epilogue: C/D layout col=lane&15, row=(lane>>4)*4+reg
#pragma unroll
  for (int qm = 0; qm < 2; qm++)
#pragma unroll
  for (int qn = 0; qn < 2; qn++)
#pragma unroll
  for (int mi = 0; mi < 4; mi++)
#pragma unroll
  for (int ni = 0; ni < 2; ni++) {
    f32x4 v = acc[qm][qn][mi][ni];
    const int col = tileN + qn * 128 + wcol + ni * 16 + l16;
    const int rowb = tileM + qm * 128 + wrow + mi * 16 + quad * 4;
#pragma unroll
    for (int r = 0; r < 4; r++) {
      const int row = rowb + r;
      const float val = v[r] * alpha;
      size_t dst;
      if (MODE == 0) {
        // dest[(h*16+b)][s][e]: h=col>>9, b=row&15, s=row>>4, e=col&511
        dst = (((size_t)((col >> 9) * 16 + (row & 15)) * 512 + (size_t)(row >> 4)) * 512)
              + (size_t)(col & 511);
      } else {
        dst = cBase + (size_t)row * ldc + (size_t)col;
      }
      if (CF32) ((float*)Cout)[dst] = val;
      else      ((bf16*)Cout)[dst] = __float2bfloat16(val);
    }
  }
}

#undef GROUP
#undef MM
#undef RD_A
#undef RD_B
#undef STG_A
#undef STG_B

// ---- fused scores + softmax (round-3 kernel, verified): per head,
// P = softmax(Q K^T * alpha), fp32 + bf16 outputs ----
#define BK 32
#define SSLOT 20480
__global__ __launch_bounds__(512, 2) void scores_softmax(
    const bf16* __restrict__ Q, const bf16* __restrict__ Kh,
    float* __restrict__ P, bf16* __restrict__ Pb, float alpha)
{
  __shared__ bf16 lds[3 * SSLOT];

  const int tid  = threadIdx.x;
  const int lane = tid & 63;
  const int wave = tid >> 6;
  const int quad = lane >> 4;
  const int l16  = lane & 15;

  int bid = blockIdx.z * 4 + blockIdx.y;
  bid = (bid & 7) * 32 + (bid >> 3);
  const int by = bid & 3;
  const int bz = bid >> 2;

  const size_t aBase = (size_t)bz * 262144;
  const size_t bBase = (size_t)bz * 262144;
  const size_t cBase = (size_t)(bz & 15) * 1048576 + (size_t)(bz >> 4) * 512;
  const int tileM = by * 128;

  const int sRow = tid >> 2;
  const int sQz  = (tid & 3) ^ ((tid >> 3) & 3);
  const int sCol = sQz * 8;
  const size_t aOff = aBase + (size_t)(tileM + sRow) * 512 + sCol;
  const size_t bOff = bBase + (size_t)sRow * 512 + sCol;
  const int t8 = tid * 8;

  const int warpRow = (wave >> 2) * 64;
  const int warpCol = (wave & 3) * 128;
  int offA[4], offB[8];
#pragma unroll
  for (int mi = 0; mi < 4; mi++) {
    const int R = warpRow + mi * 16 + l16;
    offA[mi] = R * 32 + ((quad ^ ((R >> 1) & 3)) * 8);
  }
#pragma unroll
  for (int ni = 0; ni < 8; ni++) {
    const int R = warpCol + ni * 16 + l16;
    offB[ni] = 4096 + R * 32 + ((quad ^ ((R >> 1) & 3)) * 8);
  }

  f32x4 acc[4][8] = {};

#pragma unroll
  for (int p = 0; p < 2; ++p) {
    bf16* base = lds + p * SSLOT;
    const int ks = p * BK;
    async16(Q + aOff + ks, base + t8);
#pragma unroll
    for (int c = 0; c < 4; c++)
      async16(Kh + bOff + c * 65536 + ks, base + 4096 + c * 4096 + t8);
  }
  asm volatile("s_waitcnt vmcnt(5)" ::: "memory");
  __builtin_amdgcn_s_barrier();

  for (int g = 0; g < 16; ++g) {
    if (g + 2 < 16) {
      bf16* base = lds + ((g + 2) % 3) * SSLOT;
      const int ks = (g + 2) * BK;
      async16(Q + aOff + ks, base + t8);
#pragma unroll
      for (int c = 0; c < 4; c++)
        async16(Kh + bOff + c * 65536 + ks, base + 4096 + c * 4096 + t8);
    }

    const bf16* lb = lds + (g % 3) * SSLOT;
    s16x8 af[4], bfr[8];
#pragma unroll
    for (int mi = 0; mi < 4; mi++) af[mi] = *(const s16x8*)(lb + offA[mi]);
#pragma unroll
    for (int ni = 0; ni < 8; ni++) bfr[ni] = *(const s16x8*)(lb + offB[ni]);

    __builtin_amdgcn_s_setprio(1);
#pragma unroll
    for (int mi = 0; mi < 4; mi++)
#pragma unroll
      for (int ni = 0; ni < 8; ni++)
        acc[mi][ni] = __builtin_amdgcn_mfma_f32_16x16x32_bf16(af[mi], bfr[ni], acc[mi][ni], 0, 0, 0);
    __builtin_amdgcn_s_setprio(0);

    if (g + 2 < 16) {
      asm volatile("s_waitcnt vmcnt(5)" ::: "memory");
      __builtin_amdgcn_s_barrier();
    } else if (g + 1 < 16) {
      asm volatile("s_waitcnt vmcnt(0)" ::: "memory");
      __builtin_amdgcn_s_barrier();
    }
  }

  __syncthreads();
  float* red  = (float*)lds;
  float* red2 = red + 512;
  const int wv = wave & 3;

#pragma unroll
  for (int mi = 0; mi < 4; mi++)
#pragma unroll
    for (int ni = 0; ni < 8; ni++) acc[mi][ni] *= alpha;

  f32x4 gm[4];
#pragma unroll
  for (int mi = 0; mi < 4; mi++) {
    f32x4 mx = acc[mi][0];
#pragma unroll
    for (int ni = 1; ni < 8; ni++) mx = vmax4(mx, acc[mi][ni]);
#pragma unroll
    for (int off = 1; off <= 8; off <<= 1) {
      f32x4 o;
#pragma unroll
      for (int r = 0; r < 4; r++) o[r] = __shfl_xor(mx[r], off, 64);
      mx = vmax4(mx, o);
    }
    if (l16 == 0) {
      const int rw = warpRow + mi * 16 + quad * 4;
#pragma unroll
      for (int r = 0; r < 4; r++) red[(rw + r) * 4 + wv] = mx[r];
    }
  }
  __syncthreads();
#pragma unroll
  for (int mi = 0; mi < 4; mi++) {
    const int rw = warpRow + mi * 16 + quad * 4;
#pragma unroll
    for (int r = 0; r < 4; r++) {
      f32x4 p = *(const f32x4*)&red[(rw + r) * 4];
      gm[mi][r] = fmaxf(fmaxf(p[0], p[1]), fmaxf(p[2], p[3]));
    }
  }
  f32x4 sm[4] = {};
#pragma unroll
  for (int mi = 0; mi < 4; mi++)
#pragma unroll
    for (int ni = 0; ni < 8; ni++) {
      f32x4 v = acc[mi][ni];
#pragma unroll
      for (int r = 0; r < 4; r++) v[r] = __expf(v[r] - gm[mi][r]);
      acc[mi][ni] = v;
      sm[mi] += v;
    }
#pragma unroll
  for (int mi = 0; mi < 4; mi++) {
#pragma unroll
    for (int off = 1; off <= 8; off <<= 1) {
      f32x4 o;
#pragma unroll
      for (int r = 0; r < 4; r++) o[r] = __shfl_xor(sm[mi][r], off, 64);
      sm[mi] += o;
    }
    if (l16 == 0) {
      const int rw = warpRow + mi * 16 + quad * 4;
#pragma unroll
      for (int r = 0; r < 4; r++) red2[(rw + r) * 4 + wv] = sm[mi][r];
    }
  }
  __syncthreads();
#pragma unroll
  for (int mi = 0; mi < 4; mi++) {
    const int rw = warpRow + mi * 16 + quad * 4;
#pragma unroll
    for (int r = 0; r < 4; r++) {
      f32x4 p = *(const f32x4*)&red2[(rw + r) * 4];
      gm[mi][r] = 1.f / (p[0] + p[1] + p[2] + p[3]);
    }
  }
#pragma unroll
  for (int mi = 0; mi < 4; mi++)
#pragma unroll
    for (int ni = 0; ni < 8; ni++) {
      const int col = warpCol + ni * 16 + l16;
#pragma unroll
      for (int r = 0; r < 4; r++) {
        const int row = tileM + warpRow + mi * 16 + quad * 4 + r;
        const size_t idx = cBase + (size_t)row * 2048 + col;
        const float val = acc[mi][ni][r] * gm[mi][r];
        P[idx]  = val;
        Pb[idx] = __float2bfloat16(val);
      }
    }
}

// ---- fp32 -> bf16 convert: per-instruction full coalescing (16B/lane,
// lane stride 16B), 4 independent grid-strided loads per body (~16 VGPR so
// the scheduler keeps all 4 in flight), nontemporal (single-use streams).
// Requires n4 % (4*gridDim.x*256) == 0 (all our sizes: 4.19M/1.05M chunks
// with gridDim.x=1024 -> 4 or 1 iterations exactly). ----
struct Conv6 {
  const float* src[6];
  bf16* dst[6];
  int n4[6];  // element count / 4
};

__global__ __launch_bounds__(256) void convert6(Conv6 a) {
  const int t = blockIdx.y;
  const float* __restrict__ src = a.src[t];
  bf16* __restrict__ dst = a.dst[t];
  const int n4 = a.n4[t];
  const int stride = gridDim.x * 256;
  const f32x4* __restrict__ s4 = (const f32x4*)src;
  s16x4* __restrict__ d4 = (s16x4*)dst;
  for (int i = blockIdx.x * 256 + threadIdx.x; i < n4; i += 4 * stride) {
    f32x4 x0 = __builtin_nontemporal_load(s4 + i);
    f32x4 x1 = __builtin_nontemporal_load(s4 + i + stride);
    f32x4 x2 = __builtin_nontemporal_load(s4 + i + 2 * stride);
    f32x4 x3 = __builtin_nontemporal_load(s4 + i + 3 * stride);
    s16x4 r0, r1, r2, r3;
#pragma unroll
    for (int k = 0; k < 4; k++) {
      r0[k] = f2b(x0[k]); r1[k] = f2b(x1[k]);
      r2[k] = f2b(x2[k]); r3[k] = f2b(x3[k]);
    }
    __builtin_nontemporal_store(r0, d4 + i);
    __builtin_nontemporal_store(r1, d4 + i + stride);
    __builtin_nontemporal_store(r2, d4 + i + 2 * stride);
    __builtin_nontemporal_store(r3, d4 + i + 3 * stride);
  }
}

// batched 512x512 bf16 transpose: VT[n][e][t] = V[n][t][e]
__global__ __launch_bounds__(256) void transpose512(const bf16* __restrict__ V,
                                                    bf16* __restrict__ VT) {
  __shared__ bf16 tile[32][33];
  const int n = blockIdx.z;
  const bf16* src = V + (size_t)n * 262144;
  bf16* dst = VT + (size_t)n * 262144;
  const int x = blockIdx.x * 32 + threadIdx.x;
#pragma unroll
  for (int i = 0; i < 32; i += 8)
    tile[threadIdx.y + i][threadIdx.x] =
        src[(size_t)(blockIdx.y * 32 + threadIdx.y + i) * 512 + x];
  __syncthreads();
  const int tcol = blockIdx.y * 32 + threadIdx.x;
#pragma unroll
  for (int i = 0; i < 32; i += 8)
    dst[(size_t)(blockIdx.x * 32 + threadIdx.y + i) * 512 + tcol] =
        tile[threadIdx.x][threadIdx.y + i];
}

extern "C" void kernel_launch(void* const* d_in, const int* in_sizes, int n_in,
                              void* d_out, int out_size, void* d_ws, size_t ws_size,
                              hipStream_t stream) {
  const float* query = (const float*)d_in[0];  // fp32 (512,16,2048)
  const float* key   = (const float*)d_in[1];
  const float* value = (const float*)d_in[2];
  const float* Wq = (const float*)d_in[3];     // fp32 (2048,2048)
  const float* Wk = (const float*)d_in[4];
  const float* Wv = (const float*)d_in[5];
  const float* Wo = (const float*)d_in[6];
  float* out = (float*)d_out;
  float* P   = out + 16777216;

  // 32MB scratch slots. Plan (no producer/consumer overlap at any step):
  //  qb->ws0, kb->ws1, vb->p0, Wq/Wk/Wv->p1 | Qh->o0, Kh->o1, Vh->ws0
  //  scores: o0,o1 -> P(fp32) + Pb->ws1 | transpose: ws0 -> VT@o0
  //  PV: ws1 x o0 -> X@ws0 | Wo->ws1 | final: ws0 x ws1 -> out@(o0,o1)
  bf16* ws0 = (bf16*)d_ws;
  bf16* ws1 = ws0 + 16777216;
  bf16* o0  = (bf16*)d_out;
  bf16* o1  = o0 + 16777216;
  bf16* p0  = (bf16*)P;
  bf16* p1  = p0 + 16777216;

  const dim3 blk(256);
  const dim3 gblk(512);
  const float inv_sqrt_hd = 0.04419417382415922f;  // 1/sqrt(512)

  // 1. batch-convert q,k,v + Wq,Wk,Wv to bf16
  Conv6 c;
  c.src[0] = query; c.dst[0] = ws0;           c.n4[0] = 4194304;
  c.src[1] = key;   c.dst[1] = ws1;           c.n4[1] = 4194304;
  c.src[2] = value; c.dst[2] = p0;            c.n4[2] = 4194304;
  c.src[3] = Wq;    c.dst[3] = p1;            c.n4[3] = 1048576;
  c.src[4] = Wk;    c.dst[4] = p1 + 4194304;  c.n4[4] = 1048576;
  c.src[5] = Wv;    c.dst[5] = p1 + 8388608;  c.n4[5] = 1048576;
  convert6<<<dim3(1024, 6), blk, 0, stream>>>(c);

  // 2. projections: (8192x2048) @ W^T, scatter to (H*B,S,hd) bf16
  gemm8<0, false><<<dim3(8, 32, 1), gblk, 0, stream>>>(ws0, p1,           o0,  2048, 2048, 2048, 0, 1.0f);
  gemm8<0, false><<<dim3(8, 32, 1), gblk, 0, stream>>>(ws1, p1 + 4194304, o1,  2048, 2048, 2048, 0, 1.0f);
  gemm8<0, false><<<dim3(8, 32, 1), gblk, 0, stream>>>(p0,  p1 + 8388608, ws0, 2048, 2048, 2048, 0, 1.0f);

  // 3. fused scores+softmax: P fp32 (final attn layout) + Pb bf16 -> ws1
  scores_softmax<<<dim3(1, 4, 64), gblk, 0, stream>>>(o0, o1, P, ws1, inv_sqrt_hd);

  // 4. V(ws0) -> VT @ o0 (Q heads dead)
  transpose512<<<dim3(16, 16, 64), dim3(32, 8), 0, stream>>>(ws0, o0);

  // 5. PV: A = Pb (ws1, 2048-stride), B = VT (o0) -> X bf16 (B,H,S,hd) @ ws0
  gemm8<2, false><<<dim3(2, 2, 64), gblk, 0, stream>>>(ws1, o0, ws0, 512, 2048, 512, 512, 1.0f);

  // 6. convert Wo -> ws1 (Pb dead)
  Conv6 cw;
  for (int i = 0; i < 6; i++) { cw.src[i] = Wo; cw.dst[i] = ws1; cw.n4[i] = 1048576; }
  convert6<<<dim3(1024, 1), blk, 0, stream>>>(cw);

  // 7. final: out = X @ Wo^T fp32 @ (o0,o1) region; reads only ws -> no race
  gemm8<3, true><<<dim3(8, 32, 1), gblk, 0, stream>>>(ws0, ws1, out, 2048, 2048, 2048, 2048, 1.0f);
}